// Round 13
// baseline (374.737 us; speedup 1.0000x reference)
//
#include <hip/hip_runtime.h>

#define LOG2E 1.4426950408889634f
#define SCALE 0.6830207f   // 2048^(-0.05)

typedef __attribute__((ext_vector_type(8))) _Float16 f16x8;
typedef __attribute__((ext_vector_type(4))) _Float16 f16x4;
typedef __attribute__((ext_vector_type(4))) float f32x4;

// Workgroup barrier WITHOUT the vmcnt(0) drain __syncthreads carries.
// LDS visibility needs lgkmcnt(0); outstanding global loads stay in flight.
__device__ __forceinline__ void wg_barrier() {
  asm volatile("s_waitcnt lgkmcnt(0)\n\ts_barrier" ::: "memory");
}

// ---- prep: W (3x [2048][128] fp32) -> fp16 MFMA B-frag layout ----
__global__ __launch_bounds__(256) void prep_wf(const float* __restrict__ Wq,
    const float* __restrict__ Wk, const float* __restrict__ Wv,
    _Float16* __restrict__ Wf) {
  int t = blockIdx.x * 256 + threadIdx.x;   // 0..98303
  int lane = t & 63;
  int nt = (t >> 6) % 24;
  int kc = t / (64 * 24);
  int g = lane >> 4, c = lane & 15;
  int n = nt * 16 + c;
  const float* W = (n < 128) ? Wq : ((n < 256) ? Wk : Wv);
  int nn = n & 127;
  f16x8 o;
#pragma unroll
  for (int j = 0; j < 8; ++j) {
    int k = kc * 32 + g * 8 + j;
    o[j] = (_Float16)W[k * 128 + nn];
  }
  *(f16x8*)(Wf + (size_t)t * 8) = o;
}

// ---- projection: BM=16, BK=64, 256 threads (4 waves, 1mt x 6nt each).
// Grid 1024 = 4 blocks/CU -> 16 waves/CU (2x the BM=32 version's 8).
// proj is a latency-bound convoy (MfmaUtil 8.6%, VALUBusy 5.3% at BM=64);
// wave-stream count is the proven lever. Same staging/prefetch/barrier
// rhythm and B-frag mapping as the verified BM=32 kernel.
__global__ __launch_bounds__(256, 4) void proj(const float* __restrict__ x,
    const _Float16* __restrict__ Wf,
    _Float16* __restrict__ qo, _Float16* __restrict__ ko,
    _Float16* __restrict__ vTo) {
  __shared__ __align__(16) _Float16 As[2][16 * 72];   // [buf][m][k0..63] pad 72
  int tid = threadIdx.x;
  int wave = tid >> 6, lane = tid & 63;
  int g = lane >> 4, c = lane & 15;
  int m0 = blockIdx.x * 16;
  int wn = wave * 6;                 // 4 waves x 6 nt = 24 nt tiles
  const f32x4 fz = {0.f, 0.f, 0.f, 0.f};
  f32x4 acc[6];
#pragma unroll
  for (int q = 0; q < 6; ++q) acc[q] = fz;

  int r = tid >> 4, c4 = tid & 15;   // 16 rows x 16 chunks of 4 floats
  const float* xp = x + (size_t)(m0 + r) * 2048 + c4 * 4;
  float4 pa[4];
#pragma unroll
  for (int z = 0; z < 4; ++z) pa[z] = *(const float4*)(xp + z * 64);
  {
    f16x4 h4;
    h4[0] = (_Float16)pa[0].x; h4[1] = (_Float16)pa[0].y;
    h4[2] = (_Float16)pa[0].z; h4[3] = (_Float16)pa[0].w;
    *(f16x4*)(&As[0][0] + r * 72 + c4 * 4) = h4;
  }
  wg_barrier();

#pragma unroll 4
  for (int kb = 0; kb < 32; ++kb) {
    if (kb + 1 < 32) {
      int s = (kb + 1) & 3;
      f16x4 h4;
      h4[0] = (_Float16)pa[s].x; h4[1] = (_Float16)pa[s].y;
      h4[2] = (_Float16)pa[s].z; h4[3] = (_Float16)pa[s].w;
      *(f16x4*)(&As[(kb + 1) & 1][0] + r * 72 + c4 * 4) = h4;
    }
    if (kb + 4 < 32) {
      pa[kb & 3] = *(const float4*)(xp + (kb + 4) * 64);
    }
    const _Float16* Ab = &As[kb & 1][0];
#pragma unroll
    for (int kcl = 0; kcl < 2; ++kcl) {
      f16x8 af = *(const f16x8*)(Ab + c * 72 + kcl * 32 + g * 8);
#pragma unroll
      for (int nt = 0; nt < 6; ++nt) {
        size_t boff = ((size_t)((kb * 2 + kcl) * 24 + wn + nt) * 64 + lane) * 8;
        f16x8 bf = *(const f16x8*)(Wf + boff);
        acc[nt] = __builtin_amdgcn_mfma_f32_16x16x32_f16(af, bf, acc[nt], 0, 0, 0);
      }
    }
    wg_barrier();
  }
#pragma unroll
  for (int nt = 0; nt < 6; ++nt) {
    int n = (wn + nt) * 16 + c;
    int mat = n >> 7, col = n & 127;
#pragma unroll
    for (int i = 0; i < 4; ++i) {
      int row = m0 + g * 4 + i;
      _Float16 hv = (_Float16)acc[nt][i];
      if (mat == 0)      qo[(size_t)row * 128 + col] = hv;
      else if (mat == 1) ko[(size_t)row * 128 + col] = hv;
      else               vTo[(size_t)col * 16384 + row] = hv;
    }
  }
}

// ---- flash attention partials: round-9 verified 64-KV loop (reg-staged,
// double-buffered padded LDS, Ps roundtrip, wg_barrier, chunk=8 grid,
// XCD pinning, fp16 Op). Measured 109 us / VGPR 76 / 45KB LDS. ----
__global__ __launch_bounds__(256, 3) void attn_part(
    const _Float16* __restrict__ qg, const _Float16* __restrict__ kg,
    const _Float16* __restrict__ vT,
    _Float16* __restrict__ Op, float* __restrict__ Ml) {
  __shared__ __align__(16) _Float16 Ks[64 * 136];   // [kv][h] pad 136
  __shared__ __align__(16) _Float16 Vt[128 * 72];   // [h][kv] pad 72
  __shared__ __align__(16) _Float16 Ps[4][16 * 72]; // per-wave P [q][kv] pad 72
  int tid = threadIdx.x;
  int wave = tid >> 6, lane = tid & 63;
  int g = lane >> 4, c = lane & 15;
  int up = blockIdx.x;
  int xcd = up & 7, slot = up >> 3;
  int b = xcd >> 1;                  // batch pinned to XCD pair
  int t = (xcd & 1) * 144 + slot;    // 0..287 chunk id within batch
  int u = b * 288 + t;               // logical partial index
  // t -> (qt, ch): band k holds qts [8k,8k+7], each with k+1 chunks of 8 tiles
  int k = 0, ob = 0;
  while (t >= ob + 8 * (k + 1)) { ob += 8 * (k + 1); ++k; }
  int qt = 8 * k + (t - ob) / (k + 1);
  int ch = (t - ob) % (k + 1);
  int q0 = qt * 64;
  int jbeg = ch * 8, jend = min(jbeg + 8, qt + 1);
  size_t base = (size_t)b * 4096 * 128;

  f16x8 qf[4];
#pragma unroll
  for (int kc = 0; kc < 4; ++kc)
    qf[kc] = *(const f16x8*)(qg + base + (size_t)(q0 + wave * 16 + c) * 128 + kc * 32 + g * 8);

  const f32x4 fz = {0.f, 0.f, 0.f, 0.f};
  f32x4 o[8];
#pragma unroll
  for (int hh = 0; hh < 8; ++hh) o[hh] = fz;
  float mrow = -1e30f, lrow = 0.f;   // this lane's q-row = wave*16 + c

  int kr = tid >> 4, kc8 = tid & 15;  // K staging: 16 rows x 16 8-elem chunks
  int vh = tid >> 3, vt8 = tid & 7;   // V staging: 32 h-rows x 8 chunks
  uint4 rk[4], rv[4];
#pragma unroll
  for (int z = 0; z < 4; ++z) {
    rk[z] = *(const uint4*)(kg + base + (size_t)(jbeg * 64 + z * 16 + kr) * 128 + kc8 * 8);
    rv[z] = *(const uint4*)(vT + (size_t)(z * 32 + vh) * 16384 + b * 4096 + jbeg * 64 + vt8 * 8);
  }

  for (int j = jbeg; j < jend; ++j) {
    wg_barrier();   // all waves done reading Ks/Vt from previous iter
#pragma unroll
    for (int z = 0; z < 4; ++z) {
      *(uint4*)(Ks + (z * 16 + kr) * 136 + kc8 * 8) = rk[z];
      *(uint4*)(Vt + (z * 32 + vh) * 72 + vt8 * 8) = rv[z];
    }
    if (j + 1 < jend) {
#pragma unroll
      for (int z = 0; z < 4; ++z) {
        rk[z] = *(const uint4*)(kg + base + (size_t)((j + 1) * 64 + z * 16 + kr) * 128 + kc8 * 8);
        rv[z] = *(const uint4*)(vT + (size_t)(z * 32 + vh) * 16384 + b * 4096 + (j + 1) * 64 + vt8 * 8);
      }
    }
    wg_barrier();   // staging visible

    f32x4 s[4];
#pragma unroll
    for (int mt = 0; mt < 4; ++mt) s[mt] = fz;
#pragma unroll
    for (int kc = 0; kc < 4; ++kc) {
#pragma unroll
      for (int mt = 0; mt < 4; ++mt) {
        f16x8 kf = *(const f16x8*)(Ks + (mt * 16 + c) * 136 + kc * 32 + g * 8);
        s[mt] = __builtin_amdgcn_mfma_f32_16x16x32_f16(kf, qf[kc], s[mt], 0, 0, 0);
      }
    }
    bool diag = (j == qt);
    float tmax = -1e30f;
#pragma unroll
    for (int mt = 0; mt < 4; ++mt)
#pragma unroll
      for (int i = 0; i < 4; ++i) {
        float v = s[mt][i] * SCALE;
        if (diag && (mt * 16 + g * 4 + i) > (wave * 16 + c)) v = -1e30f;
        s[mt][i] = v;
        tmax = fmaxf(tmax, v);
      }
    tmax = fmaxf(tmax, __shfl_xor(tmax, 16, 64));
    tmax = fmaxf(tmax, __shfl_xor(tmax, 32, 64));
    float mnew = fmaxf(mrow, tmax);
    float alpha = __builtin_amdgcn_exp2f((mrow - mnew) * LOG2E);
    float rsum = 0.f;
#pragma unroll
    for (int mt = 0; mt < 4; ++mt)
#pragma unroll
      for (int i = 0; i < 4; ++i) {
        float e = __builtin_amdgcn_exp2f((s[mt][i] - mnew) * LOG2E);
        s[mt][i] = e;                       // reuse s as P
        rsum += e;
      }
    rsum += __shfl_xor(rsum, 16, 64);
    rsum += __shfl_xor(rsum, 32, 64);
    lrow = lrow * alpha + rsum;
    mrow = mnew;
    int srcb = (lane & 48) + ((lane & 48) >> 2);
    float ar[4];
#pragma unroll
    for (int i = 0; i < 4; ++i) ar[i] = __shfl(alpha, srcb + i, 64);
#pragma unroll
    for (int hh = 0; hh < 8; ++hh)
#pragma unroll
      for (int i = 0; i < 4; ++i) o[hh][i] *= ar[i];
#pragma unroll
    for (int mt = 0; mt < 4; ++mt) {
      f16x4 pk;
#pragma unroll
      for (int i = 0; i < 4; ++i) pk[i] = (_Float16)s[mt][i];
      *(f16x4*)(&Ps[wave][0] + c * 72 + mt * 16 + g * 4) = pk;
    }
#pragma unroll
    for (int kc = 0; kc < 2; ++kc) {
      f16x8 pf = *(const f16x8*)(&Ps[wave][0] + c * 72 + kc * 32 + g * 8);
#pragma unroll
      for (int hh = 0; hh < 8; ++hh) {
        f16x8 vf = *(const f16x8*)(Vt + (hh * 16 + c) * 72 + kc * 32 + g * 8);
        o[hh] = __builtin_amdgcn_mfma_f32_16x16x32_f16(pf, vf, o[hh], 0, 0, 0);
      }
    }
  }
#pragma unroll
  for (int hh = 0; hh < 8; ++hh)
#pragma unroll
    for (int i = 0; i < 4; ++i) {
      int row = wave * 16 + g * 4 + i;
      Op[(size_t)u * 8192 + row * 128 + hh * 16 + c] = (_Float16)o[hh][i];
    }
  if (lane < 16) {
    int row = wave * 16 + lane;
    Ml[(size_t)u * 128 + row * 2]     = mrow;
    Ml[(size_t)u * 128 + row * 2 + 1] = lrow;
  }
}

// ---- merge partials -> out: 1024 blocks (4 per (b,qt), 4/CU TLP),
// f16x4 loads / float4 stores, XCD-pinned to the pair that wrote Op. ----
__global__ __launch_bounds__(256) void attn_merge(const _Float16* __restrict__ Op,
    const float* __restrict__ Ml, float* __restrict__ out) {
  int up = blockIdx.x;               // 0..1023
  int xcd = up & 7, slot = up >> 3;  // slot 0..127
  int b = xcd >> 1;                  // same XCD pair as attn_part's batch b
  int idx = (xcd & 1) * 128 + slot;  // 0..255 within batch
  int qt = idx >> 2, z = idx & 3;    // q-tile + quarter
  int k = qt >> 3;
  int nch = k + 1;
  int bb = 4 * k * (k + 1) + (qt & 7) * (k + 1);
  int u0 = b * 288 + bb;
  __shared__ float w[8][64];
  int tid = threadIdx.x;
  if (tid < 64) {
    float m[8], l[8];
    float M = -1e30f;
    for (int uu = 0; uu < nch; ++uu) {
      m[uu] = Ml[(size_t)(u0 + uu) * 128 + tid * 2];
      l[uu] = Ml[(size_t)(u0 + uu) * 128 + tid * 2 + 1];
      M = fmaxf(M, m[uu]);
    }
    float L = 0.f;
    for (int uu = 0; uu < nch; ++uu) {
      float e = __builtin_amdgcn_exp2f((m[uu] - M) * LOG2E);
      w[uu][tid] = e;
      L += l[uu] * e;
    }
    float iL = 1.0f / L;
    for (int uu = 0; uu < nch; ++uu) w[uu][tid] *= iL;
  }
  __syncthreads();
#pragma unroll
  for (int it = 0; it < 2; ++it) {
    int e0 = ((z * 2 + it) * 256 + tid) * 4;   // 0..8188, covers 8192 exactly
    int row = e0 >> 7;
    const _Float16* opp = Op + (size_t)u0 * 8192 + e0;
    float ax = 0.f, ay = 0.f, az = 0.f, aw = 0.f;
    for (int uu = 0; uu < nch; ++uu) {
      f16x4 v = *(const f16x4*)(opp + (size_t)uu * 8192);
      float ww = w[uu][row];
      ax += ww * (float)v[0]; ay += ww * (float)v[1];
      az += ww * (float)v[2]; aw += ww * (float)v[3];
    }
    float4 r = {ax, ay, az, aw};
    *(float4*)(out + (size_t)b * 524288 + (size_t)qt * 8192 + e0) = r;
  }
}

extern "C" void kernel_launch(void* const* d_in, const int* in_sizes, int n_in,
                              void* d_out, int out_size, void* d_ws, size_t ws_size,
                              hipStream_t stream) {
  const float* x  = (const float*)d_in[0];
  const float* Wq = (const float*)d_in[1];
  const float* Wk = (const float*)d_in[2];
  const float* Wv = (const float*)d_in[3];
  const size_t NTOK = (size_t)16384 * 128;
  _Float16* q  = (_Float16*)d_ws;
  _Float16* k  = q + NTOK;
  _Float16* vT = k + NTOK;
  _Float16* Wf = vT + NTOK;                       // 786432 fp16
  _Float16* Op = Wf + (size_t)786432;             // 1152 * 8192 fp16
  float* Ml = (float*)(Op + (size_t)1152 * 8192); // 1152 * 128 f32
  prep_wf<<<384, 256, 0, stream>>>(Wq, Wk, Wv, Wf);
  proj<<<1024, 256, 0, stream>>>(x, Wf, q, k, vT);
  attn_part<<<1152, 256, 0, stream>>>(q, k, vT, Op, Ml);
  attn_merge<<<1024, 256, 0, stream>>>(Op, Ml, (float*)d_out);
}

// Round 14
// 328.742 us; speedup vs baseline: 1.1399x; 1.1399x over previous
//
#include <hip/hip_runtime.h>

#define LOG2E 1.4426950408889634f
#define SCALE 0.6830207f   // 2048^(-0.05)

typedef __attribute__((ext_vector_type(8))) _Float16 f16x8;
typedef __attribute__((ext_vector_type(4))) _Float16 f16x4;
typedef __attribute__((ext_vector_type(4))) float f32x4;

// Workgroup barrier WITHOUT the vmcnt(0) drain __syncthreads carries.
// LDS visibility needs lgkmcnt(0); outstanding global loads stay in flight.
__device__ __forceinline__ void wg_barrier() {
  asm volatile("s_waitcnt lgkmcnt(0)\n\ts_barrier" ::: "memory");
}

// ---- prep: W (3x [2048][128] fp32) -> fp16 MFMA B-frag layout ----
__global__ __launch_bounds__(256) void prep_wf(const float* __restrict__ Wq,
    const float* __restrict__ Wk, const float* __restrict__ Wv,
    _Float16* __restrict__ Wf) {
  int t = blockIdx.x * 256 + threadIdx.x;   // 0..98303
  int lane = t & 63;
  int nt = (t >> 6) % 24;
  int kc = t / (64 * 24);
  int g = lane >> 4, c = lane & 15;
  int n = nt * 16 + c;
  const float* W = (n < 128) ? Wq : ((n < 256) ? Wk : Wv);
  int nn = n & 127;
  f16x8 o;
#pragma unroll
  for (int j = 0; j < 8; ++j) {
    int k = kc * 32 + g * 8 + j;
    o[j] = (_Float16)W[k * 128 + nn];
  }
  *(f16x8*)(Wf + (size_t)t * 8) = o;
}

// ---- projection: BM=32, BK=64, fp16; B-fragments double-buffered in
// REGISTERS with distance-1 prefetch (12 x f16x8 per buffer) -- the L2
// load latency that dominated proj (MfmaUtil 8%) hides under the K-step.
// Grid-bound at 2 blocks/CU so the +96 VGPR is free (2 waves/SIMD holds
// to ~256 VGPR). Same verified staging/barrier rhythm as round 9.
__global__ __launch_bounds__(256, 2) void proj(const float* __restrict__ x,
    const _Float16* __restrict__ Wf,
    _Float16* __restrict__ qo, _Float16* __restrict__ ko,
    _Float16* __restrict__ vTo) {
  __shared__ __align__(16) _Float16 As[2][32 * 72];
  int tid = threadIdx.x;
  int wave = tid >> 6, lane = tid & 63;
  int g = lane >> 4, c = lane & 15;
  int m0 = blockIdx.x * 32;
  int wn = wave * 6;
  const f32x4 fz = {0.f, 0.f, 0.f, 0.f};
  f32x4 acc[2][6];
#pragma unroll
  for (int a = 0; a < 2; ++a)
#pragma unroll
    for (int q = 0; q < 6; ++q) acc[a][q] = fz;

  int r = tid >> 3, c4 = tid & 7;
  const float* xp = x + (size_t)(m0 + r) * 2048 + c4 * 8;
  float4 pa[4], pb[4];
#pragma unroll
  for (int z = 0; z < 4; ++z) {
    pa[z] = *(const float4*)(xp + z * 64);
    pb[z] = *(const float4*)(xp + z * 64 + 4);
  }
  {
    f16x8 h8;
    h8[0] = (_Float16)pa[0].x; h8[1] = (_Float16)pa[0].y;
    h8[2] = (_Float16)pa[0].z; h8[3] = (_Float16)pa[0].w;
    h8[4] = (_Float16)pb[0].x; h8[5] = (_Float16)pb[0].y;
    h8[6] = (_Float16)pb[0].z; h8[7] = (_Float16)pb[0].w;
    *(f16x8*)(&As[0][0] + r * 72 + c4 * 8) = h8;
  }
  // B prologue: fragments for kb=0 into buffer 0
  f16x8 bf[2][2][6];
#pragma unroll
  for (int kcl = 0; kcl < 2; ++kcl)
#pragma unroll
    for (int nt = 0; nt < 6; ++nt)
      bf[0][kcl][nt] = *(const f16x8*)(Wf +
          ((size_t)(kcl * 24 + wn + nt) * 64 + lane) * 8);
  wg_barrier();

#pragma unroll 4
  for (int kb = 0; kb < 32; ++kb) {
    // issue next K-step's B loads (registers, wave-local; latency hides
    // under this K-step's 24 MFMAs)
    if (kb + 1 < 32) {
#pragma unroll
      for (int kcl = 0; kcl < 2; ++kcl)
#pragma unroll
        for (int nt = 0; nt < 6; ++nt)
          bf[(kb + 1) & 1][kcl][nt] = *(const f16x8*)(Wf +
              ((size_t)(((kb + 1) * 2 + kcl) * 24 + wn + nt) * 64 + lane) * 8);
    }
    if (kb + 1 < 32) {
      int s = (kb + 1) & 3;
      f16x8 h8;
      h8[0] = (_Float16)pa[s].x; h8[1] = (_Float16)pa[s].y;
      h8[2] = (_Float16)pa[s].z; h8[3] = (_Float16)pa[s].w;
      h8[4] = (_Float16)pb[s].x; h8[5] = (_Float16)pb[s].y;
      h8[6] = (_Float16)pb[s].z; h8[7] = (_Float16)pb[s].w;
      *(f16x8*)(&As[(kb + 1) & 1][0] + r * 72 + c4 * 8) = h8;
    }
    if (kb + 4 < 32) {
      pa[kb & 3] = *(const float4*)(xp + (kb + 4) * 64);
      pb[kb & 3] = *(const float4*)(xp + (kb + 4) * 64 + 4);
    }
    const _Float16* Ab = &As[kb & 1][0];
#pragma unroll
    for (int kcl = 0; kcl < 2; ++kcl) {
      f16x8 af[2];
#pragma unroll
      for (int mt = 0; mt < 2; ++mt)
        af[mt] = *(const f16x8*)(Ab + (mt * 16 + c) * 72 + kcl * 32 + g * 8);
#pragma unroll
      for (int nt = 0; nt < 6; ++nt) {
#pragma unroll
        for (int mt = 0; mt < 2; ++mt)
          acc[mt][nt] = __builtin_amdgcn_mfma_f32_16x16x32_f16(
              af[mt], bf[kb & 1][kcl][nt], acc[mt][nt], 0, 0, 0);
      }
    }
    wg_barrier();
  }
#pragma unroll
  for (int mt = 0; mt < 2; ++mt) {
#pragma unroll
    for (int nt = 0; nt < 6; ++nt) {
      int n = (wn + nt) * 16 + c;
      int mat = n >> 7, col = n & 127;
#pragma unroll
      for (int i = 0; i < 4; ++i) {
        int row = m0 + mt * 16 + g * 4 + i;
        _Float16 hv = (_Float16)acc[mt][nt][i];
        if (mat == 0)      qo[(size_t)row * 128 + col] = hv;
        else if (mat == 1) ko[(size_t)row * 128 + col] = hv;
        else               vTo[(size_t)col * 16384 + row] = hv;
      }
    }
  }
}

// ---- flash attention partials: round-9 verified 64-KV loop (reg-staged,
// double-buffered padded LDS, Ps roundtrip, wg_barrier, chunk=8 grid,
// XCD pinning, fp16 Op). Measured 109 us / VGPR 76 / 45KB LDS. ----
__global__ __launch_bounds__(256, 3) void attn_part(
    const _Float16* __restrict__ qg, const _Float16* __restrict__ kg,
    const _Float16* __restrict__ vT,
    _Float16* __restrict__ Op, float* __restrict__ Ml) {
  __shared__ __align__(16) _Float16 Ks[64 * 136];   // [kv][h] pad 136
  __shared__ __align__(16) _Float16 Vt[128 * 72];   // [h][kv] pad 72
  __shared__ __align__(16) _Float16 Ps[4][16 * 72]; // per-wave P [q][kv] pad 72
  int tid = threadIdx.x;
  int wave = tid >> 6, lane = tid & 63;
  int g = lane >> 4, c = lane & 15;
  int up = blockIdx.x;
  int xcd = up & 7, slot = up >> 3;
  int b = xcd >> 1;                  // batch pinned to XCD pair
  int t = (xcd & 1) * 144 + slot;    // 0..287 chunk id within batch
  int u = b * 288 + t;               // logical partial index
  // t -> (qt, ch): band k holds qts [8k,8k+7], each with k+1 chunks of 8 tiles
  int k = 0, ob = 0;
  while (t >= ob + 8 * (k + 1)) { ob += 8 * (k + 1); ++k; }
  int qt = 8 * k + (t - ob) / (k + 1);
  int ch = (t - ob) % (k + 1);
  int q0 = qt * 64;
  int jbeg = ch * 8, jend = min(jbeg + 8, qt + 1);
  size_t base = (size_t)b * 4096 * 128;

  f16x8 qf[4];
#pragma unroll
  for (int kc = 0; kc < 4; ++kc)
    qf[kc] = *(const f16x8*)(qg + base + (size_t)(q0 + wave * 16 + c) * 128 + kc * 32 + g * 8);

  const f32x4 fz = {0.f, 0.f, 0.f, 0.f};
  f32x4 o[8];
#pragma unroll
  for (int hh = 0; hh < 8; ++hh) o[hh] = fz;
  float mrow = -1e30f, lrow = 0.f;   // this lane's q-row = wave*16 + c

  int kr = tid >> 4, kc8 = tid & 15;  // K staging: 16 rows x 16 8-elem chunks
  int vh = tid >> 3, vt8 = tid & 7;   // V staging: 32 h-rows x 8 chunks
  uint4 rk[4], rv[4];
#pragma unroll
  for (int z = 0; z < 4; ++z) {
    rk[z] = *(const uint4*)(kg + base + (size_t)(jbeg * 64 + z * 16 + kr) * 128 + kc8 * 8);
    rv[z] = *(const uint4*)(vT + (size_t)(z * 32 + vh) * 16384 + b * 4096 + jbeg * 64 + vt8 * 8);
  }

  for (int j = jbeg; j < jend; ++j) {
    wg_barrier();   // all waves done reading Ks/Vt from previous iter
#pragma unroll
    for (int z = 0; z < 4; ++z) {
      *(uint4*)(Ks + (z * 16 + kr) * 136 + kc8 * 8) = rk[z];
      *(uint4*)(Vt + (z * 32 + vh) * 72 + vt8 * 8) = rv[z];
    }
    if (j + 1 < jend) {
#pragma unroll
      for (int z = 0; z < 4; ++z) {
        rk[z] = *(const uint4*)(kg + base + (size_t)((j + 1) * 64 + z * 16 + kr) * 128 + kc8 * 8);
        rv[z] = *(const uint4*)(vT + (size_t)(z * 32 + vh) * 16384 + b * 4096 + (j + 1) * 64 + vt8 * 8);
      }
    }
    wg_barrier();   // staging visible

    f32x4 s[4];
#pragma unroll
    for (int mt = 0; mt < 4; ++mt) s[mt] = fz;
#pragma unroll
    for (int kc = 0; kc < 4; ++kc) {
#pragma unroll
      for (int mt = 0; mt < 4; ++mt) {
        f16x8 kf = *(const f16x8*)(Ks + (mt * 16 + c) * 136 + kc * 32 + g * 8);
        s[mt] = __builtin_amdgcn_mfma_f32_16x16x32_f16(kf, qf[kc], s[mt], 0, 0, 0);
      }
    }
    bool diag = (j == qt);
    float tmax = -1e30f;
#pragma unroll
    for (int mt = 0; mt < 4; ++mt)
#pragma unroll
      for (int i = 0; i < 4; ++i) {
        float v = s[mt][i] * SCALE;
        if (diag && (mt * 16 + g * 4 + i) > (wave * 16 + c)) v = -1e30f;
        s[mt][i] = v;
        tmax = fmaxf(tmax, v);
      }
    tmax = fmaxf(tmax, __shfl_xor(tmax, 16, 64));
    tmax = fmaxf(tmax, __shfl_xor(tmax, 32, 64));
    float mnew = fmaxf(mrow, tmax);
    float alpha = __builtin_amdgcn_exp2f((mrow - mnew) * LOG2E);
    float rsum = 0.f;
#pragma unroll
    for (int mt = 0; mt < 4; ++mt)
#pragma unroll
      for (int i = 0; i < 4; ++i) {
        float e = __builtin_amdgcn_exp2f((s[mt][i] - mnew) * LOG2E);
        s[mt][i] = e;                       // reuse s as P
        rsum += e;
      }
    rsum += __shfl_xor(rsum, 16, 64);
    rsum += __shfl_xor(rsum, 32, 64);
    lrow = lrow * alpha + rsum;
    mrow = mnew;
    int srcb = (lane & 48) + ((lane & 48) >> 2);
    float ar[4];
#pragma unroll
    for (int i = 0; i < 4; ++i) ar[i] = __shfl(alpha, srcb + i, 64);
#pragma unroll
    for (int hh = 0; hh < 8; ++hh)
#pragma unroll
      for (int i = 0; i < 4; ++i) o[hh][i] *= ar[i];
#pragma unroll
    for (int mt = 0; mt < 4; ++mt) {
      f16x4 pk;
#pragma unroll
      for (int i = 0; i < 4; ++i) pk[i] = (_Float16)s[mt][i];
      *(f16x4*)(&Ps[wave][0] + c * 72 + mt * 16 + g * 4) = pk;
    }
#pragma unroll
    for (int kc = 0; kc < 2; ++kc) {
      f16x8 pf = *(const f16x8*)(&Ps[wave][0] + c * 72 + kc * 32 + g * 8);
#pragma unroll
      for (int hh = 0; hh < 8; ++hh) {
        f16x8 vf = *(const f16x8*)(Vt + (hh * 16 + c) * 72 + kc * 32 + g * 8);
        o[hh] = __builtin_amdgcn_mfma_f32_16x16x32_f16(pf, vf, o[hh], 0, 0, 0);
      }
    }
  }
#pragma unroll
  for (int hh = 0; hh < 8; ++hh)
#pragma unroll
    for (int i = 0; i < 4; ++i) {
      int row = wave * 16 + g * 4 + i;
      Op[(size_t)u * 8192 + row * 128 + hh * 16 + c] = (_Float16)o[hh][i];
    }
  if (lane < 16) {
    int row = wave * 16 + lane;
    Ml[(size_t)u * 128 + row * 2]     = mrow;
    Ml[(size_t)u * 128 + row * 2 + 1] = lrow;
  }
}

// ---- merge partials -> out: 1024 blocks (4 per (b,qt), 4/CU TLP),
// f16x4 loads / float4 stores, XCD-pinned to the pair that wrote Op. ----
__global__ __launch_bounds__(256) void attn_merge(const _Float16* __restrict__ Op,
    const float* __restrict__ Ml, float* __restrict__ out) {
  int up = blockIdx.x;               // 0..1023
  int xcd = up & 7, slot = up >> 3;  // slot 0..127
  int b = xcd >> 1;                  // same XCD pair as attn_part's batch b
  int idx = (xcd & 1) * 128 + slot;  // 0..255 within batch
  int qt = idx >> 2, z = idx & 3;    // q-tile + quarter
  int k = qt >> 3;
  int nch = k + 1;
  int bb = 4 * k * (k + 1) + (qt & 7) * (k + 1);
  int u0 = b * 288 + bb;
  __shared__ float w[8][64];
  int tid = threadIdx.x;
  if (tid < 64) {
    float m[8], l[8];
    float M = -1e30f;
    for (int uu = 0; uu < nch; ++uu) {
      m[uu] = Ml[(size_t)(u0 + uu) * 128 + tid * 2];
      l[uu] = Ml[(size_t)(u0 + uu) * 128 + tid * 2 + 1];
      M = fmaxf(M, m[uu]);
    }
    float L = 0.f;
    for (int uu = 0; uu < nch; ++uu) {
      float e = __builtin_amdgcn_exp2f((m[uu] - M) * LOG2E);
      w[uu][tid] = e;
      L += l[uu] * e;
    }
    float iL = 1.0f / L;
    for (int uu = 0; uu < nch; ++uu) w[uu][tid] *= iL;
  }
  __syncthreads();
#pragma unroll
  for (int it = 0; it < 2; ++it) {
    int e0 = ((z * 2 + it) * 256 + tid) * 4;   // 0..8188, covers 8192 exactly
    int row = e0 >> 7;
    const _Float16* opp = Op + (size_t)u0 * 8192 + e0;
    float ax = 0.f, ay = 0.f, az = 0.f, aw = 0.f;
    for (int uu = 0; uu < nch; ++uu) {
      f16x4 v = *(const f16x4*)(opp + (size_t)uu * 8192);
      float ww = w[uu][row];
      ax += ww * (float)v[0]; ay += ww * (float)v[1];
      az += ww * (float)v[2]; aw += ww * (float)v[3];
    }
    float4 r = {ax, ay, az, aw};
    *(float4*)(out + (size_t)b * 524288 + (size_t)qt * 8192 + e0) = r;
  }
}

extern "C" void kernel_launch(void* const* d_in, const int* in_sizes, int n_in,
                              void* d_out, int out_size, void* d_ws, size_t ws_size,
                              hipStream_t stream) {
  const float* x  = (const float*)d_in[0];
  const float* Wq = (const float*)d_in[1];
  const float* Wk = (const float*)d_in[2];
  const float* Wv = (const float*)d_in[3];
  const size_t NTOK = (size_t)16384 * 128;
  _Float16* q  = (_Float16*)d_ws;
  _Float16* k  = q + NTOK;
  _Float16* vT = k + NTOK;
  _Float16* Wf = vT + NTOK;                       // 786432 fp16
  _Float16* Op = Wf + (size_t)786432;             // 1152 * 8192 fp16
  float* Ml = (float*)(Op + (size_t)1152 * 8192); // 1152 * 128 f32
  prep_wf<<<384, 256, 0, stream>>>(Wq, Wk, Wv, Wf);
  proj<<<512, 256, 0, stream>>>(x, Wf, q, k, vT);
  attn_part<<<1152, 256, 0, stream>>>(q, k, vT, Op, Ml);
  attn_merge<<<1024, 256, 0, stream>>>(Op, Ml, (float*)d_out);
}